// Round 1
// baseline (1902.718 us; speedup 1.0000x reference)
//
#include <hip/hip_runtime.h>
#include <hip/hip_bf16.h>

#define S 4
#define NDIM 2048
#define MDIM 4096
#define NN (NDIM*NDIM)
#define TOTAL (S*NN)
#define EPSF 1e-10f
#define NCHUNK 16
#define RPC 128
#define NITER 21

typedef __bf16 bf16x8 __attribute__((ext_vector_type(8)));
typedef float f32x4 __attribute__((ext_vector_type(4)));

__device__ __forceinline__ void gld16(const void* g, void* l) {
  __builtin_amdgcn_global_load_lds(
      (const __attribute__((address_space(1))) unsigned int*)g,
      (__attribute__((address_space(3))) unsigned int*)l, 16, 0, 0);
}

__device__ __forceinline__ unsigned short f2bf(float f) {
  __hip_bfloat16 h = __float2bfloat16(f);
  return *reinterpret_cast<unsigned short*>(&h);
}

// la[s][n][m] = log_alpha[n][m] - log(EPS - log(U + EPS))
extern "C" __global__ __launch_bounds__(256) void k_init(
    const float* __restrict__ la0, const float* __restrict__ gum,
    float* __restrict__ la) {
  int stride = gridDim.x * blockDim.x;
  for (int i = blockIdx.x * blockDim.x + threadIdx.x; i < TOTAL / 4; i += stride) {
    float4 g = reinterpret_cast<const float4*>(gum)[i];
    float4 a = reinterpret_cast<const float4*>(la0)[i & (NN / 4 - 1)];
    float4 r;
    r.x = a.x - __logf(EPSF - __logf(g.x + EPSF));
    r.y = a.y - __logf(EPSF - __logf(g.y + EPSF));
    r.z = a.z - __logf(EPSF - __logf(g.z + EPSF));
    r.w = a.w - __logf(EPSF - __logf(g.w + EPSF));
    reinterpret_cast<float4*>(la)[i] = r;
  }
}

// Partial column logsumexp: online (max,sum) over RPC rows per chunk.
extern "C" __global__ __launch_bounds__(256) void k_colpart(
    const float* __restrict__ la, float* __restrict__ pmax, float* __restrict__ psum) {
  int ct = blockIdx.x & 7;           // 8 column tiles of 256
  int rc = (blockIdx.x >> 3) & 15;   // 16 row chunks of 128
  int s  = blockIdx.x >> 7;
  int col = ct * 256 + threadIdx.x;
  const float* base = la + (size_t)s * NN + (size_t)rc * RPC * NDIM + col;
  float m = -INFINITY, sum = 0.f;
  for (int r = 0; r < RPC; ++r) {
    float v = base[(size_t)r * NDIM];
    if (v <= m) {
      sum += __expf(v - m);
    } else {
      sum = sum * __expf(m - v) + 1.f;
      m = v;
    }
  }
  int pi = (s * NCHUNK + rc) * NDIM + col;
  pmax[pi] = m;
  psum[pi] = sum;
}

// Combine 16 partials per column -> colc[s][m] = col LSE
extern "C" __global__ __launch_bounds__(256) void k_colcomb(
    const float* __restrict__ pmax, const float* __restrict__ psum,
    float* __restrict__ colc) {
  int i = blockIdx.x * 256 + threadIdx.x;  // over S*NDIM = 8192
  int s = i >> 11, col = i & (NDIM - 1);
  float m = -INFINITY, sum = 0.f;
#pragma unroll
  for (int rc = 0; rc < NCHUNK; ++rc) {
    int pi = (s * NCHUNK + rc) * NDIM + col;
    float pm = pmax[pi], ps = psum[pi];
    if (pm <= m) {
      sum += ps * __expf(pm - m);
    } else {
      sum = sum * __expf(m - pm) + ps;
      m = pm;
    }
  }
  colc[i] = m + __logf(sum);
}

// Per row: v = la - colc; r = LSE(v); la = v - r.  One wave per row.
extern "C" __global__ __launch_bounds__(64) void k_row(
    float* __restrict__ la, const float* __restrict__ colc) {
  int s = blockIdx.x >> 11;
  int row = blockIdx.x & (NDIM - 1);
  float* rp = la + ((size_t)s * NDIM + row) * NDIM;
  const float* cc = colc + (size_t)s * NDIM;
  int l = threadIdx.x;
  float4 v[8];
  float m = -INFINITY;
#pragma unroll
  for (int q = 0; q < 8; ++q) {
    float4 x4 = reinterpret_cast<const float4*>(rp)[l + q * 64];
    float4 c4 = reinterpret_cast<const float4*>(cc)[l + q * 64];
    x4.x -= c4.x; x4.y -= c4.y; x4.z -= c4.z; x4.w -= c4.w;
    v[q] = x4;
    m = fmaxf(m, fmaxf(fmaxf(x4.x, x4.y), fmaxf(x4.z, x4.w)));
  }
#pragma unroll
  for (int o = 32; o; o >>= 1) m = fmaxf(m, __shfl_xor(m, o));
  float sum = 0.f;
#pragma unroll
  for (int q = 0; q < 8; ++q)
    sum += __expf(v[q].x - m) + __expf(v[q].y - m) + __expf(v[q].z - m) + __expf(v[q].w - m);
#pragma unroll
  for (int o = 32; o; o >>= 1) sum += __shfl_xor(sum, o);
  float r = m + __logf(sum);
#pragma unroll
  for (int q = 0; q < 8; ++q) {
    float4 o4 = v[q];
    o4.x -= r; o4.y -= r; o4.z -= r; o4.w -= r;
    reinterpret_cast<float4*>(rp)[l + q * 64] = o4;
  }
}

// P^T[s][m][n] = bf16(exp(la[s][n][m])) via 64x64 LDS tile transpose
extern "C" __global__ __launch_bounds__(256) void k_expT(
    const float* __restrict__ la, unsigned short* __restrict__ pt) {
  __shared__ float tile[64][65];
  int s = blockIdx.z, nt = blockIdx.y, mt = blockIdx.x;
  const float* src = la + ((size_t)s * NDIM + nt * 64) * NDIM + mt * 64;
  int cx = threadIdx.x & 15, ry = threadIdx.x >> 4;
#pragma unroll
  for (int p = 0; p < 4; ++p) {
    int r = ry + p * 16;
    float4 vv = *reinterpret_cast<const float4*>(src + (size_t)r * NDIM + cx * 4);
    tile[r][cx * 4 + 0] = vv.x;
    tile[r][cx * 4 + 1] = vv.y;
    tile[r][cx * 4 + 2] = vv.z;
    tile[r][cx * 4 + 3] = vv.w;
  }
  __syncthreads();
  unsigned short* dst = pt + ((size_t)s * NDIM + mt * 64) * NDIM + nt * 64;
#pragma unroll
  for (int p = 0; p < 4; ++p) {
    int mr = ry + p * 16;
    ushort4 o;
    o.x = f2bf(__expf(tile[cx * 4 + 0][mr]));
    o.y = f2bf(__expf(tile[cx * 4 + 1][mr]));
    o.z = f2bf(__expf(tile[cx * 4 + 2][mr]));
    o.w = f2bf(__expf(tile[cx * 4 + 3][mr]));
    *reinterpret_cast<ushort4*>(dst + (size_t)mr * NDIM + cx * 4) = o;
  }
}

extern "C" __global__ __launch_bounds__(256) void k_xbf(
    const float* __restrict__ x, unsigned short* __restrict__ xb) {
  int stride = gridDim.x * blockDim.x;
  for (int i = blockIdx.x * 256 + threadIdx.x; i < (MDIM * NDIM) / 4; i += stride) {
    float4 vv = reinterpret_cast<const float4*>(x)[i];
    ushort4 o;
    o.x = f2bf(vv.x); o.y = f2bf(vv.y); o.z = f2bf(vv.z); o.w = f2bf(vv.w);
    reinterpret_cast<ushort4*>(xb)[i] = o;
  }
}

// out[s][b][m] = sum_n x[b][n] * P[s][n][m];  A = x (M x K), B^T = P^T (N x K)
// 128x128 tile, BK=32, 4 waves (2x2 of 64x64), mfma_f32_16x16x32_bf16
extern "C" __global__ __launch_bounds__(256) void k_gemm(
    const unsigned short* __restrict__ xb, const unsigned short* __restrict__ pt,
    float* __restrict__ out) {
  __shared__ __align__(16) unsigned short lA[128 * 32];
  __shared__ __align__(16) unsigned short lB[128 * 32];
  const int K = NDIM;
  int s = blockIdx.z, mt = blockIdx.y, nt = blockIdx.x;
  int tid = threadIdx.x;
  int w = tid >> 6, l = tid & 63;
  const unsigned short* Ab = xb + (size_t)(mt * 128) * K;
  const unsigned short* Bb = pt + ((size_t)s * NDIM + nt * 128) * K;
  int row0 = tid >> 2, kc = tid & 3;
  int wm = (w >> 1) * 64, wn = (w & 1) * 64;
  int arow = l & 15, akc = l >> 4;
  f32x4 acc[4][4];
#pragma unroll
  for (int i = 0; i < 4; ++i)
#pragma unroll
    for (int j = 0; j < 4; ++j) acc[i][j] = (f32x4){0.f, 0.f, 0.f, 0.f};

  const unsigned short* a0 = Ab + (size_t)row0 * K + kc * 8;
  const unsigned short* a1 = Ab + (size_t)(row0 + 64) * K + kc * 8;
  const unsigned short* b0 = Bb + (size_t)row0 * K + kc * 8;
  const unsigned short* b1 = Bb + (size_t)(row0 + 64) * K + kc * 8;

  for (int k0 = 0; k0 < K; k0 += 32) {
    __syncthreads();
    gld16(a0 + k0, lA + (size_t)tid * 8);
    gld16(a1 + k0, lA + (size_t)(256 + tid) * 8);
    gld16(b0 + k0, lB + (size_t)tid * 8);
    gld16(b1 + k0, lB + (size_t)(256 + tid) * 8);
    __syncthreads();
    bf16x8 af[4], bfr[4];
#pragma unroll
    for (int i = 0; i < 4; ++i)
      af[i] = *reinterpret_cast<const bf16x8*>(lA + ((wm + i * 16 + arow) * 32 + akc * 8));
#pragma unroll
    for (int j = 0; j < 4; ++j)
      bfr[j] = *reinterpret_cast<const bf16x8*>(lB + ((wn + j * 16 + arow) * 32 + akc * 8));
#pragma unroll
    for (int i = 0; i < 4; ++i)
#pragma unroll
      for (int j = 0; j < 4; ++j)
        acc[i][j] = __builtin_amdgcn_mfma_f32_16x16x32_bf16(af[i], bfr[j], acc[i][j], 0, 0, 0);
  }
  float* ob = out + ((size_t)s * MDIM + mt * 128 + wm) * NDIM + nt * 128 + wn;
#pragma unroll
  for (int i = 0; i < 4; ++i)
#pragma unroll
    for (int j = 0; j < 4; ++j)
#pragma unroll
      for (int r = 0; r < 4; ++r)
        ob[(size_t)(i * 16 + akc * 4 + r) * NDIM + j * 16 + arow] = acc[i][j][r];
}

extern "C" void kernel_launch(void* const* d_in, const int* in_sizes, int n_in,
                              void* d_out, int out_size, void* d_ws, size_t ws_size,
                              hipStream_t stream) {
  const float* x   = (const float*)d_in[0];
  const float* la0 = (const float*)d_in[1];
  const float* gum = (const float*)d_in[2];
  float* out = (float*)d_out;

  char* ws = (char*)d_ws;
  float* la   = (float*)ws;                                   // 64 MB
  float* pmax = (float*)(ws + (size_t)TOTAL * 4);             // 512 KB
  float* psum = pmax + S * NCHUNK * NDIM;                     // 512 KB
  float* colc = psum + S * NCHUNK * NDIM;                     // 32 KB
  unsigned short* ptb = (unsigned short*)(colc + S * NDIM);   // 32 MB (bf16 P^T)
  unsigned short* xbb = ptb + (size_t)TOTAL;                  // 16 MB (bf16 x)

  k_init<<<2048, 256, 0, stream>>>(la0, gum, la);
  for (int it = 0; it < NITER; ++it) {
    k_colpart<<<512, 256, 0, stream>>>(la, pmax, psum);
    k_colcomb<<<32, 256, 0, stream>>>(pmax, psum, colc);
    k_row<<<S * NDIM, 64, 0, stream>>>(la, colc);
  }
  k_expT<<<dim3(NDIM / 64, NDIM / 64, S), 256, 0, stream>>>(la, ptb);
  k_xbf<<<2048, 256, 0, stream>>>(x, xbb);
  k_gemm<<<dim3(NDIM / 128, MDIM / 128, S), 256, 0, stream>>>(xbb, ptb, out);
}

// Round 3
// 988.196 us; speedup vs baseline: 1.9254x; 1.9254x over previous
//
#include <hip/hip_runtime.h>
#include <hip/hip_bf16.h>

#define S 4
#define NDIM 2048
#define MDIM 4096
#define NN (NDIM*NDIM)
#define TOTAL (S*NN)
#define EPSF 1e-10f
#define NCHUNK 128
#define ROWS 16      // rows per chunk = NDIM / NCHUNK
#define NITER 21

typedef __bf16 bf16x8 __attribute__((ext_vector_type(8)));
typedef float f32x4 __attribute__((ext_vector_type(4)));

__device__ __forceinline__ void gld16(const void* g, void* l) {
  __builtin_amdgcn_global_load_lds(
      (const __attribute__((address_space(1))) unsigned int*)g,
      (__attribute__((address_space(3))) unsigned int*)l, 16, 0, 0);
}

__device__ __forceinline__ unsigned short f2bf(float f) {
  __hip_bfloat16 h = __float2bfloat16(f);
  return *reinterpret_cast<unsigned short*>(&h);
}

// E[s][n][m] = exp(log_alpha[n][m] - log(EPS - log(U + EPS)))
extern "C" __global__ __launch_bounds__(256) void k_init(
    const float* __restrict__ la0, const float* __restrict__ gum,
    float* __restrict__ E) {
  int stride = gridDim.x * blockDim.x;
  for (int i = blockIdx.x * blockDim.x + threadIdx.x; i < TOTAL / 4; i += stride) {
    float4 g = reinterpret_cast<const float4*>(gum)[i];
    float4 a = reinterpret_cast<const float4*>(la0)[i & (NN / 4 - 1)];
    float4 r;
    r.x = __expf(a.x - __logf(EPSF - __logf(g.x + EPSF)));
    r.y = __expf(a.y - __logf(EPSF - __logf(g.y + EPSF)));
    r.z = __expf(a.z - __logf(EPSF - __logf(g.z + EPSF)));
    r.w = __expf(a.w - __logf(EPSF - __logf(g.w + EPSF)));
    reinterpret_cast<float4*>(E)[i] = r;
  }
}

// Initial partial column sums (eu = 1): pcol[s][rc][m] = sum_{n in chunk} E[s][n][m]
extern "C" __global__ __launch_bounds__(256) void k_colpart0(
    const float* __restrict__ E, float* __restrict__ pcol) {
  int bid = blockIdx.x;
  int s = bid >> 7, rc = bid & (NCHUNK - 1);
  const float* Ec = E + (size_t)s * NN + (size_t)rc * ROWS * NDIM;
  int tid = threadIdx.x;
#pragma unroll
  for (int j = 0; j < 2; ++j) {
    int c0 = j * 1024 + 4 * tid;
    float4 acc = {0.f, 0.f, 0.f, 0.f};
#pragma unroll
    for (int n = 0; n < ROWS; ++n) {
      float4 e4 = *reinterpret_cast<const float4*>(Ec + (size_t)n * NDIM + c0);
      acc.x += e4.x; acc.y += e4.y; acc.z += e4.z; acc.w += e4.w;
    }
    *reinterpret_cast<float4*>(pcol + ((size_t)bid * NDIM) + c0) = acc;
  }
}

// ev[s][m] = 1 / sum_rc pcol[s][rc][m]
extern "C" __global__ __launch_bounds__(256) void k_comb(
    const float* __restrict__ pcol, float* __restrict__ ev) {
  int i = blockIdx.x * 256 + threadIdx.x;  // S*NDIM = 8192
  int s = i >> 11, m = i & (NDIM - 1);
  float sum = 0.f;
#pragma unroll 16
  for (int rc = 0; rc < NCHUNK; ++rc)
    sum += pcol[((size_t)(s * NCHUNK + rc)) * NDIM + m];
  ev[i] = 1.f / sum;
}

// Fused: row sums (-> eu) for this chunk, then partial col sums using fresh eu.
extern "C" __global__ __launch_bounds__(256) void k_fused(
    const float* __restrict__ E, const float* __restrict__ ev,
    float* __restrict__ eu, float* __restrict__ pcol, int docol) {
  __shared__ float sev[NDIM];
  __shared__ float seu[ROWS];
  int bid = blockIdx.x;
  int s = bid >> 7, rc = bid & (NCHUNK - 1);
  int tid = threadIdx.x;
  const float* evs = ev + (size_t)s * NDIM;
  // stage ev into LDS (2 float4 per thread)
#pragma unroll
  for (int j = 0; j < 2; ++j) {
    int c = (j * 256 + tid) * 4;
    *reinterpret_cast<float4*>(&sev[c]) = *reinterpret_cast<const float4*>(evs + c);
  }
  __syncthreads();
  const float* Ec = E + (size_t)s * NN + (size_t)rc * ROWS * NDIM;
  int w = tid >> 6, l = tid & 63;
  // step 1: each wave does 4 rows; rowsum[n] = sum_m E[n][m]*ev[m]
#pragma unroll
  for (int rr = 0; rr < 4; ++rr) {
    int lrow = w * 4 + rr;
    const float* Er = Ec + (size_t)lrow * NDIM;
    float4 acc = {0.f, 0.f, 0.f, 0.f};
#pragma unroll
    for (int q = 0; q < 8; ++q) {
      int idx = q * 256 + 4 * l;
      float4 e4 = *reinterpret_cast<const float4*>(Er + idx);
      float4 v4 = *reinterpret_cast<const float4*>(&sev[idx]);
      acc.x += e4.x * v4.x; acc.y += e4.y * v4.y;
      acc.z += e4.z * v4.z; acc.w += e4.w * v4.w;
    }
    float sum = acc.x + acc.y + acc.z + acc.w;
#pragma unroll
    for (int o = 32; o; o >>= 1) sum += __shfl_xor(sum, o);
    float r = 1.f / sum;
    if (l == 0) {
      seu[lrow] = r;
      eu[(size_t)s * NDIM + rc * ROWS + lrow] = r;
    }
  }
  __syncthreads();
  // step 2: partial col sums over this (L2-hot) chunk with fresh eu
  if (docol) {
#pragma unroll
    for (int j = 0; j < 2; ++j) {
      int c0 = j * 1024 + 4 * tid;
      float4 acc = {0.f, 0.f, 0.f, 0.f};
#pragma unroll
      for (int n = 0; n < ROWS; ++n) {
        float u = seu[n];
        float4 e4 = *reinterpret_cast<const float4*>(Ec + (size_t)n * NDIM + c0);
        acc.x += e4.x * u; acc.y += e4.y * u; acc.z += e4.z * u; acc.w += e4.w * u;
      }
      *reinterpret_cast<float4*>(pcol + ((size_t)bid * NDIM) + c0) = acc;
    }
  }
}

// PT[s][m][n] = bf16(E[s][n][m] * eu[s][n] * ev[s][m]) via 64x64 LDS transpose
extern "C" __global__ __launch_bounds__(256) void k_scaleT(
    const float* __restrict__ E, const float* __restrict__ eu,
    const float* __restrict__ ev, unsigned short* __restrict__ pt) {
  __shared__ float tile[64][65];
  int s = blockIdx.z, nt = blockIdx.y, mt = blockIdx.x;
  const float* src = E + ((size_t)s * NDIM + nt * 64) * NDIM + mt * 64;
  const float* eus = eu + (size_t)s * NDIM + nt * 64;
  const float* evs = ev + (size_t)s * NDIM + mt * 64;
  int cx = threadIdx.x & 15, ry = threadIdx.x >> 4;
  float4 ev4 = *reinterpret_cast<const float4*>(evs + cx * 4);
#pragma unroll
  for (int p = 0; p < 4; ++p) {
    int r = ry + p * 16;
    float ur = eus[r];
    float4 vv = *reinterpret_cast<const float4*>(src + (size_t)r * NDIM + cx * 4);
    tile[r][cx * 4 + 0] = vv.x * ur * ev4.x;
    tile[r][cx * 4 + 1] = vv.y * ur * ev4.y;
    tile[r][cx * 4 + 2] = vv.z * ur * ev4.z;
    tile[r][cx * 4 + 3] = vv.w * ur * ev4.w;
  }
  __syncthreads();
  unsigned short* dst = pt + ((size_t)s * NDIM + mt * 64) * NDIM + nt * 64;
#pragma unroll
  for (int p = 0; p < 4; ++p) {
    int mr = ry + p * 16;
    ushort4 o;
    o.x = f2bf(tile[cx * 4 + 0][mr]);
    o.y = f2bf(tile[cx * 4 + 1][mr]);
    o.z = f2bf(tile[cx * 4 + 2][mr]);
    o.w = f2bf(tile[cx * 4 + 3][mr]);
    *reinterpret_cast<ushort4*>(dst + (size_t)mr * NDIM + cx * 4) = o;
  }
}

extern "C" __global__ __launch_bounds__(256) void k_xbf(
    const float* __restrict__ x, unsigned short* __restrict__ xb) {
  int stride = gridDim.x * blockDim.x;
  for (int i = blockIdx.x * 256 + threadIdx.x; i < (MDIM * NDIM) / 4; i += stride) {
    float4 vv = reinterpret_cast<const float4*>(x)[i];
    ushort4 o;
    o.x = f2bf(vv.x); o.y = f2bf(vv.y); o.z = f2bf(vv.z); o.w = f2bf(vv.w);
    reinterpret_cast<ushort4*>(xb)[i] = o;
  }
}

// out[s][b][m] = sum_n x[b][n] * P[s][n][m];  A = x (M x K), B^T = PT (N x K)
// 128x128 tile, BK=32, 4 waves (2x2 of 64x64), mfma_f32_16x16x32_bf16
extern "C" __global__ __launch_bounds__(256) void k_gemm(
    const unsigned short* __restrict__ xb, const unsigned short* __restrict__ pt,
    float* __restrict__ out) {
  __shared__ __align__(16) unsigned short lA[128 * 32];
  __shared__ __align__(16) unsigned short lB[128 * 32];
  const int K = NDIM;
  int s = blockIdx.z, mt = blockIdx.y, nt = blockIdx.x;
  int tid = threadIdx.x;
  int w = tid >> 6, l = tid & 63;
  const unsigned short* Ab = xb + (size_t)(mt * 128) * K;
  const unsigned short* Bb = pt + ((size_t)s * NDIM + nt * 128) * K;
  int row0 = tid >> 2, kc = tid & 3;
  int wm = (w >> 1) * 64, wn = (w & 1) * 64;
  int arow = l & 15, akc = l >> 4;
  f32x4 acc[4][4];
#pragma unroll
  for (int i = 0; i < 4; ++i)
#pragma unroll
    for (int j = 0; j < 4; ++j) acc[i][j] = (f32x4){0.f, 0.f, 0.f, 0.f};

  const unsigned short* a0 = Ab + (size_t)row0 * K + kc * 8;
  const unsigned short* a1 = Ab + (size_t)(row0 + 64) * K + kc * 8;
  const unsigned short* b0 = Bb + (size_t)row0 * K + kc * 8;
  const unsigned short* b1 = Bb + (size_t)(row0 + 64) * K + kc * 8;

  for (int k0 = 0; k0 < K; k0 += 32) {
    __syncthreads();
    gld16(a0 + k0, lA + (size_t)tid * 8);
    gld16(a1 + k0, lA + (size_t)(256 + tid) * 8);
    gld16(b0 + k0, lB + (size_t)tid * 8);
    gld16(b1 + k0, lB + (size_t)(256 + tid) * 8);
    __syncthreads();
    bf16x8 af[4], bfr[4];
#pragma unroll
    for (int i = 0; i < 4; ++i)
      af[i] = *reinterpret_cast<const bf16x8*>(lA + ((wm + i * 16 + arow) * 32 + akc * 8));
#pragma unroll
    for (int j = 0; j < 4; ++j)
      bfr[j] = *reinterpret_cast<const bf16x8*>(lB + ((wn + j * 16 + arow) * 32 + akc * 8));
#pragma unroll
    for (int i = 0; i < 4; ++i)
#pragma unroll
      for (int j = 0; j < 4; ++j)
        acc[i][j] = __builtin_amdgcn_mfma_f32_16x16x32_bf16(af[i], bfr[j], acc[i][j], 0, 0, 0);
  }
  float* ob = out + ((size_t)s * MDIM + mt * 128 + wm) * NDIM + nt * 128 + wn;
#pragma unroll
  for (int i = 0; i < 4; ++i)
#pragma unroll
    for (int j = 0; j < 4; ++j)
#pragma unroll
      for (int r = 0; r < 4; ++r)
        ob[(size_t)(i * 16 + akc * 4 + r) * NDIM + j * 16 + arow] = acc[i][j][r];
}

extern "C" void kernel_launch(void* const* d_in, const int* in_sizes, int n_in,
                              void* d_out, int out_size, void* d_ws, size_t ws_size,
                              hipStream_t stream) {
  const float* x   = (const float*)d_in[0];
  const float* la0 = (const float*)d_in[1];
  const float* gum = (const float*)d_in[2];
  float* out = (float*)d_out;

  char* ws = (char*)d_ws;
  float* E = (float*)ws;                                       // 64 MB
  unsigned short* ptb = (unsigned short*)(ws + (size_t)TOTAL * 4);   // 32 MB (bf16 PT)
  float* pcol = (float*)ptb;                                   // 4 MB, overlaid (dead before PT written)
  unsigned short* xbb = (unsigned short*)(ws + (size_t)TOTAL * 6);   // 16 MB (bf16 x)
  float* ev = (float*)(ws + (size_t)TOTAL * 8);                // 32 KB
  float* eu = ev + S * NDIM;                                   // 32 KB

  k_init<<<2048, 256, 0, stream>>>(la0, gum, E);
  k_xbf<<<2048, 256, 0, stream>>>(x, xbb);

  k_colpart0<<<S * NCHUNK, 256, 0, stream>>>(E, pcol);
  k_comb<<<32, 256, 0, stream>>>(pcol, ev);
  for (int it = 1; it <= NITER; ++it) {
    k_fused<<<S * NCHUNK, 256, 0, stream>>>(E, ev, eu, pcol, it < NITER ? 1 : 0);
    if (it < NITER) k_comb<<<32, 256, 0, stream>>>(pcol, ev);
  }
  k_scaleT<<<dim3(NDIM / 64, NDIM / 64, S), 256, 0, stream>>>(E, eu, ev, ptb);
  k_gemm<<<dim3(NDIM / 128, MDIM / 128, S), 256, 0, stream>>>(xbb, ptb, out);
}